// Round 2
// baseline (494.746 us; speedup 1.0000x reference)
//
#include <hip/hip_runtime.h>

// ---------------------------------------------------------------------------
// HierarchicalRegimeController on MI355X — fp32 in/out (round-1 NaN showed
// the bf16 read of fp32 buffers: mantissa halves reinterpreted as exponents).
// PRNG: JAX threefry2x32, jax_threefry_partitionable=True:
//   split:  key_i = block(key, 0, i)
//   bits32(i) = b1 ^ b2 of block(key, hi32(i), lo32(i))
// ---------------------------------------------------------------------------

#define NB 64     // batch
#define NT 2048   // seq
#define ND 512    // d_model
#define NH 512    // hidden
#define NG 4
#define NS 6
#define NA 4

typedef unsigned int u32;

// ---------------- threefry2x32 (JAX-exact, 20 rounds) ----------------------
struct TF2 { u32 a, b; };

__host__ __device__ constexpr u32 rotl32(u32 x, int r) { return (x << r) | (x >> (32 - r)); }

__host__ __device__ constexpr TF2 tf2x32(u32 k0, u32 k1, u32 x0, u32 x1) {
  u32 ks2 = k0 ^ k1 ^ 0x1BD11BDAu;
  x0 += k0; x1 += k1;
  x0 += x1; x1 = rotl32(x1, 13); x1 ^= x0;
  x0 += x1; x1 = rotl32(x1, 15); x1 ^= x0;
  x0 += x1; x1 = rotl32(x1, 26); x1 ^= x0;
  x0 += x1; x1 = rotl32(x1, 6);  x1 ^= x0;
  x0 += k1;  x1 += ks2 + 1u;
  x0 += x1; x1 = rotl32(x1, 17); x1 ^= x0;
  x0 += x1; x1 = rotl32(x1, 29); x1 ^= x0;
  x0 += x1; x1 = rotl32(x1, 16); x1 ^= x0;
  x0 += x1; x1 = rotl32(x1, 24); x1 ^= x0;
  x0 += ks2; x1 += k0 + 2u;
  x0 += x1; x1 = rotl32(x1, 13); x1 ^= x0;
  x0 += x1; x1 = rotl32(x1, 15); x1 ^= x0;
  x0 += x1; x1 = rotl32(x1, 26); x1 ^= x0;
  x0 += x1; x1 = rotl32(x1, 6);  x1 ^= x0;
  x0 += k0;  x1 += k1 + 3u;
  x0 += x1; x1 = rotl32(x1, 17); x1 ^= x0;
  x0 += x1; x1 = rotl32(x1, 29); x1 ^= x0;
  x0 += x1; x1 = rotl32(x1, 16); x1 ^= x0;
  x0 += x1; x1 = rotl32(x1, 24); x1 ^= x0;
  x0 += k1;  x1 += ks2 + 4u;
  x0 += x1; x1 = rotl32(x1, 13); x1 ^= x0;
  x0 += x1; x1 = rotl32(x1, 15); x1 ^= x0;
  x0 += x1; x1 = rotl32(x1, 26); x1 ^= x0;
  x0 += x1; x1 = rotl32(x1, 6);  x1 ^= x0;
  x0 += ks2; x1 += k0 + 5u;
  return TF2{x0, x1};
}

// fold-like split of key(42) = (0,42): gk[i] = block(0,42, 0, i)
constexpr TF2 GKG = tf2x32(0u, 42u, 0u, 0u);  // global gumbel key
constexpr TF2 GKS = tf2x32(0u, 42u, 0u, 1u);  // sector
constexpr TF2 GKA = tf2x32(0u, 42u, 0u, 2u);  // asset

__device__ inline float gumbel32(u32 k0, u32 k1, u32 idx) {
  TF2 r = tf2x32(k0, k1, 0u, idx);
  u32 bits = r.a ^ r.b;                 // partitionable 32-bit draw
  float f = __uint_as_float((bits >> 9) | 0x3f800000u) - 1.0f;  // [0,1)
  f = fmaxf(f, 1.17549435e-38f);        // uniform(minval=tiny, maxval=1)
  return -logf(-logf(f));
}

__device__ inline float gelu_exact(float x) {
  return 0.5f * x * (1.0f + erff(x * 0.70710678118654752f));
}

// ---------------- K1: partial sums over T ----------------------------------
// grid 1024 = B(64) x 16 chunks of 128 rows; block 256; float4 loads.
__global__ __launch_bounds__(256) void k_partial(const float* __restrict__ x,
                                                 float* __restrict__ part,
                                                 float* __restrict__ klacc) {
  if (blockIdx.x == 0 && threadIdx.x < 3) klacc[threadIdx.x] = 0.0f;
  int bx = blockIdx.x;
  int b = bx >> 4, c = bx & 15;
  int tid = threadIdx.x;
  int q = tid & 127;   // which 4-col quad
  int rg = tid >> 7;   // row group 0/1
  const float* base = x + ((size_t)(b * NT + c * 128 + rg) * ND + q * 4);
  float4 acc = make_float4(0.f, 0.f, 0.f, 0.f);
#pragma unroll 8
  for (int i = 0; i < 64; ++i) {
    float4 v = *reinterpret_cast<const float4*>(base + (size_t)i * 2 * ND);
    acc.x += v.x; acc.y += v.y; acc.z += v.z; acc.w += v.w;
  }
  __shared__ float sm[2][ND];
  *reinterpret_cast<float4*>(&sm[rg][q * 4]) = acc;
  __syncthreads();
  float* p = part + (size_t)bx * ND;
  p[tid]       = sm[0][tid] + sm[1][tid];
  p[tid + 256] = sm[0][tid + 256] + sm[1][tid + 256];
}

// ---------------- K2: finalize seq_mean + telescoped diff ------------------
__global__ __launch_bounds__(256) void k_means(const float* __restrict__ part,
                                               const float* __restrict__ x,
                                               float* __restrict__ seq,
                                               float* __restrict__ diff) {
  int b = blockIdx.x, tid = threadIdx.x;
  int d = tid * 2;
  float2 s = make_float2(0.f, 0.f);
  const float* p = part + (size_t)b * 16 * ND + d;
#pragma unroll
  for (int c = 0; c < 16; ++c) {
    float2 v = *reinterpret_cast<const float2*>(p + (size_t)c * ND);
    s.x += v.x; s.y += v.y;
  }
  seq[b * ND + d]     = s.x * (1.0f / (float)NT);
  seq[b * ND + d + 1] = s.y * (1.0f / (float)NT);
  const float* x0 = x + (size_t)b * NT * ND;
  const float* xl = x0 + (size_t)(NT - 1) * ND;
  const float inv = 1.0f / (float)(NT - 1);
  diff[b * ND + d]     = (xl[d]     - x0[d])     * inv;
  diff[b * ND + d + 1] = (xl[d + 1] - x0[d + 1]) * inv;
}

// ---------------- K3: first-layer GEMMs (pre-activations) ------------------
// grid 192 = mu(3) x mtile(8 of 8 rows) x ntile(8 of 64 cols); block 256.
__global__ __launch_bounds__(256) void k_gemm1(
    const float* __restrict__ seq, const float* __restrict__ diff,
    const float* __restrict__ gW1, const float* __restrict__ gb1,
    const float* __restrict__ sW1, const float* __restrict__ sb1,
    const float* __restrict__ aW1, const float* __restrict__ ab1,
    float* __restrict__ pre) {
  int bx = blockIdx.x;
  int mu = bx >> 6; int rem = bx & 63;
  int m0 = (rem >> 3) * 8, n0 = (rem & 7) * 64;
  const float* Asrc = (mu == 2) ? diff : seq;
  const float* W = (mu == 0) ? gW1 : (mu == 1) ? sW1 : aW1;
  const float* bias = (mu == 0) ? gb1 : (mu == 1) ? sb1 : ab1;
  __shared__ float As[8][ND];
  int tid = threadIdx.x;
  for (int r = 0; r < 16; ++r) {
    int idx = r * 256 + tid;
    As[idx >> 9][idx & 511] = Asrc[(size_t)(m0 + (idx >> 9)) * ND + (idx & 511)];
  }
  __syncthreads();
  int n = n0 + (tid & 63);
  int ml = (tid >> 6) * 2;
  float a0 = 0.f, a1 = 0.f;
#pragma unroll 8
  for (int k = 0; k < ND; ++k) {
    float w = W[(size_t)k * NH + n];
    a0 += As[ml][k] * w;
    a1 += As[ml + 1][k] * w;
  }
  float bb = bias[n];
  pre[(size_t)(m0 + ml) * 1536 + mu * 512 + n]     = a0 + bb;
  pre[(size_t)(m0 + ml + 1) * 1536 + mu * 512 + n] = a1 + bb;
}

// ---------------- K4: LayerNorm + GELU activations -------------------------
__global__ __launch_bounds__(256) void k_act(const float* __restrict__ pre,
                                             const float* __restrict__ lnw,
                                             const float* __restrict__ lnb,
                                             float* __restrict__ act) {
  int b = blockIdx.x, tid = threadIdx.x;
  const float* p = pre + (size_t)b * 1536;
  float* a = act + (size_t)b * 1536;
  __shared__ float red[8];
  float v0 = p[tid], v1 = p[tid + 256];
  float s = v0 + v1;
#pragma unroll
  for (int o = 32; o > 0; o >>= 1) s += __shfl_down(s, o, 64);
  int wid = tid >> 6, lane = tid & 63;
  if (lane == 0) red[wid] = s;
  __syncthreads();
  if (tid == 0) red[0] = (red[0] + red[1] + red[2] + red[3]) * (1.0f / 512.0f);
  __syncthreads();
  float mean = red[0];
  float d0 = v0 - mean, d1 = v1 - mean;
  float q = d0 * d0 + d1 * d1;
#pragma unroll
  for (int o = 32; o > 0; o >>= 1) q += __shfl_down(q, o, 64);
  if (lane == 0) red[4 + wid] = q;
  __syncthreads();
  if (tid == 0) red[1] = (red[4] + red[5] + red[6] + red[7]) * (1.0f / 512.0f);
  __syncthreads();
  float r = 1.0f / sqrtf(red[1] + 1e-5f);
  float h0 = d0 * r * lnw[tid] + lnb[tid];
  float h1 = d1 * r * lnw[tid + 256] + lnb[tid + 256];
  a[tid] = gelu_exact(h0);
  a[tid + 256] = gelu_exact(h1);
#pragma unroll
  for (int j = 0; j < 4; ++j) {
    int idx = 512 + j * 256 + tid;
    a[idx] = gelu_exact(p[idx]);
  }
}

// ---------------- K5: second-layer GEMMs (logits) --------------------------
// grid 648 = mtile(8) x 81 ntiles (g:1, s:48, a:32); block 256.
__global__ __launch_bounds__(256) void k_gemm2(
    const float* __restrict__ act,
    const float* __restrict__ gW2, const float* __restrict__ gb2,
    const float* __restrict__ sW2, const float* __restrict__ sb2,
    const float* __restrict__ aW2, const float* __restrict__ ab2,
    float* __restrict__ lg, float* __restrict__ ls, float* __restrict__ la) {
  int bx = blockIdx.x;
  int mt = bx / 81, j = bx % 81;
  int mu, n0, N; const float *W, *bias; float* out; int ld;
  if (j == 0)       { mu = 0; n0 = 0;             N = NG;   W = gW2; bias = gb2; out = lg; ld = NG; }
  else if (j <= 48) { mu = 1; n0 = (j - 1) * 64;  N = 3072; W = sW2; bias = sb2; out = ls; ld = 3072; }
  else              { mu = 2; n0 = (j - 49) * 64; N = 2048; W = aW2; bias = ab2; out = la; ld = 2048; }
  int m0 = mt * 8;
  __shared__ float As[8][NH];
  int tid = threadIdx.x;
  for (int r = 0; r < 16; ++r) {
    int idx = r * 256 + tid;
    As[idx >> 9][idx & 511] = act[(size_t)(m0 + (idx >> 9)) * 1536 + mu * 512 + (idx & 511)];
  }
  __syncthreads();
  int nl = tid & 63;
  int ml = (tid >> 6) * 2;
  if (nl < N) {
    int n = n0 + nl;
    float a0 = 0.f, a1 = 0.f;
#pragma unroll 8
    for (int k = 0; k < NH; ++k) {
      float w = W[(size_t)k * N + n];
      a0 += As[ml][k] * w;
      a1 += As[ml + 1][k] * w;
    }
    float bb = bias[n];
    out[(size_t)(m0 + ml) * ld + n]     = a0 + bb;
    out[(size_t)(m0 + ml + 1) * ld + n] = a1 + bb;
  }
}

// ---------------- K6: gumbel-softmax + KL + gates --------------------------
// grid 256 = b(64) x fq(4); block 128 (one thread per feature f).
__global__ __launch_bounds__(128) void k_final(
    const float* __restrict__ lg, const float* __restrict__ ls,
    const float* __restrict__ la,
    const float* __restrict__ g_prior, const float* __restrict__ s_prior,
    const float* __restrict__ a_prior, const float* __restrict__ g2f,
    const float* __restrict__ semb, const float* __restrict__ aemb,
    float* __restrict__ out, float* __restrict__ klacc) {
  int bx = blockIdx.x;
  int b = bx >> 2, fq = bx & 3;
  int tid = threadIdx.x;
  __shared__ float gp[NG];
  if (tid == 0) {
    float l[NG], z[NG];
    float zm = -1e30f;
#pragma unroll
    for (int g = 0; g < NG; ++g) {
      l[g] = lg[b * NG + g];
      float gn = gumbel32(GKG.a, GKG.b, (u32)(b * NG + g));
      z[g] = (l[g] + gn) * 2.0f;  // /tau, tau=0.5
      zm = fmaxf(zm, z[g]);
    }
    float zs = 0.f;
#pragma unroll
    for (int g = 0; g < NG; ++g) { z[g] = expf(z[g] - zm); zs += z[g]; }
    float inv = 1.0f / zs;
#pragma unroll
    for (int g = 0; g < NG; ++g) gp[g] = z[g] * inv;
    if (fq == 0) {
#pragma unroll
      for (int g = 0; g < NG; ++g) out[b * NG + g] = gp[g];
      float lm = -1e30f, qm = -1e30f, q[NG];
#pragma unroll
      for (int g = 0; g < NG; ++g) {
        q[g] = g_prior[g];
        lm = fmaxf(lm, l[g]); qm = fmaxf(qm, q[g]);
      }
      float le = 0.f, qe = 0.f;
#pragma unroll
      for (int g = 0; g < NG; ++g) { le += expf(l[g] - lm); qe += expf(q[g] - qm); }
      float lls = logf(le), qls = logf(qe);
      float kl = 0.f;
#pragma unroll
      for (int g = 0; g < NG; ++g) {
        float lp = l[g] - lm - lls, lq = q[g] - qm - qls;
        kl += expf(lp) * (lp - lq);
      }
      atomicAdd(&klacc[0], kl);
    }
  }
  __syncthreads();
  int f = fq * 128 + tid;

  // ---- sector (6-way) ----
  float sl[NS], sz[NS], sp[NS];
  u32 sbase = (u32)((b * ND + f) * NS);
  const float* lsp = ls + (size_t)b * 3072 + f * NS;
  float zm = -1e30f;
#pragma unroll
  for (int s = 0; s < NS; ++s) {
    sl[s] = lsp[s];
    float gn = gumbel32(GKS.a, GKS.b, sbase + s);
    sz[s] = (sl[s] + gn) * 2.0f;
    zm = fmaxf(zm, sz[s]);
  }
  float zs = 0.f;
#pragma unroll
  for (int s = 0; s < NS; ++s) { sz[s] = expf(sz[s] - zm); zs += sz[s]; }
  float inv = 1.0f / zs;
  float* outs = out + 256 + (size_t)sbase;
#pragma unroll
  for (int s = 0; s < NS; ++s) { sp[s] = sz[s] * inv; outs[s] = sp[s]; }
  // KL sector
  float lm = -1e30f;
#pragma unroll
  for (int s = 0; s < NS; ++s) lm = fmaxf(lm, sl[s]);
  float le = 0.f;
#pragma unroll
  for (int s = 0; s < NS; ++s) le += expf(sl[s] - lm);
  float lls = logf(le);
  float q6[NS], qm = -1e30f;
#pragma unroll
  for (int s = 0; s < NS; ++s) { q6[s] = s_prior[s]; qm = fmaxf(qm, q6[s]); }
  float qe = 0.f;
#pragma unroll
  for (int s = 0; s < NS; ++s) qe += expf(q6[s] - qm);
  float qls = logf(qe);
  float klS = 0.f;
#pragma unroll
  for (int s = 0; s < NS; ++s) {
    float lp = sl[s] - lm - lls, lq = q6[s] - qm - qls;
    klS += expf(lp) * (lp - lq);
  }

  // ---- asset (4-way) ----
  float al[NA], az[NA], ap[NA];
  u32 abase = (u32)((b * ND + f) * NA);
  const float* lap = la + (size_t)b * 2048 + f * NA;
  zm = -1e30f;
#pragma unroll
  for (int a = 0; a < NA; ++a) {
    al[a] = lap[a];
    float gn = gumbel32(GKA.a, GKA.b, abase + a);
    az[a] = (al[a] + gn) * 2.0f;
    zm = fmaxf(zm, az[a]);
  }
  zs = 0.f;
#pragma unroll
  for (int a = 0; a < NA; ++a) { az[a] = expf(az[a] - zm); zs += az[a]; }
  inv = 1.0f / zs;
  float* outa = out + 196864 + (size_t)abase;
#pragma unroll
  for (int a = 0; a < NA; ++a) { ap[a] = az[a] * inv; outa[a] = ap[a]; }
  // KL asset
  lm = -1e30f;
#pragma unroll
  for (int a = 0; a < NA; ++a) lm = fmaxf(lm, al[a]);
  le = 0.f;
#pragma unroll
  for (int a = 0; a < NA; ++a) le += expf(al[a] - lm);
  lls = logf(le);
  float q4[NA]; qm = -1e30f;
#pragma unroll
  for (int a = 0; a < NA; ++a) { q4[a] = a_prior[a]; qm = fmaxf(qm, q4[a]); }
  qe = 0.f;
#pragma unroll
  for (int a = 0; a < NA; ++a) qe += expf(q4[a] - qm);
  qls = logf(qe);
  float klA = 0.f;
#pragma unroll
  for (int a = 0; a < NA; ++a) {
    float lp = al[a] - lm - lls, lq = q4[a] - qm - qls;
    klA += expf(lp) * (lp - lq);
  }

  // ---- gates ----
  float gg = 0.f;
#pragma unroll
  for (int g = 0; g < NG; ++g) gg += gp[g] * g2f[g * ND + f];
  float sg = 0.f;
#pragma unroll
  for (int s = 0; s < NS; ++s) sg += sp[s] * semb[s * ND + f];
  float ag = 0.f;
#pragma unroll
  for (int a = 0; a < NA; ++a) ag += ap[a] * aemb[a * ND + f];
  float xg = gg + sg + ag;
  out[327936 + b * ND + f] = 1.0f / (1.0f + expf(-xg));

  // ---- KL reductions (per-wave shuffle, then one atomic per wave) ----
#pragma unroll
  for (int o = 32; o > 0; o >>= 1) {
    klS += __shfl_down(klS, o, 64);
    klA += __shfl_down(klA, o, 64);
  }
  if ((tid & 63) == 0) {
    atomicAdd(&klacc[1], klS);
    atomicAdd(&klacc[2], klA);
  }
}

// ---------------- K7: KL scalars -------------------------------------------
__global__ void k_scalars(const float* __restrict__ klacc, float* __restrict__ out) {
  if (threadIdx.x == 0 && blockIdx.x == 0) {
    out[360704] = klacc[0] * (1.0f / 64.0f);
    out[360705] = klacc[1] * (1.0f / 32768.0f);
    out[360706] = klacc[2] * (1.0f / 32768.0f);
  }
}

// ---------------------------------------------------------------------------
extern "C" void kernel_launch(void* const* d_in, const int* in_sizes, int n_in,
                              void* d_out, int out_size, void* d_ws, size_t ws_size,
                              hipStream_t stream) {
  const float* x       = (const float*)d_in[0];
  const float* gW1     = (const float*)d_in[1];
  const float* gb1     = (const float*)d_in[2];
  const float* g_ln_w  = (const float*)d_in[3];
  const float* g_ln_b  = (const float*)d_in[4];
  const float* gW2     = (const float*)d_in[5];
  const float* gb2     = (const float*)d_in[6];
  const float* sW1     = (const float*)d_in[7];
  const float* sb1     = (const float*)d_in[8];
  const float* sW2     = (const float*)d_in[9];
  const float* sb2     = (const float*)d_in[10];
  const float* aW1     = (const float*)d_in[11];
  const float* ab1     = (const float*)d_in[12];
  const float* aW2     = (const float*)d_in[13];
  const float* ab2     = (const float*)d_in[14];
  const float* g_prior = (const float*)d_in[15];
  const float* s_prior = (const float*)d_in[16];
  const float* a_prior = (const float*)d_in[17];
  const float* g2f     = (const float*)d_in[18];
  const float* semb    = (const float*)d_in[19];
  const float* aemb    = (const float*)d_in[20];

  float* ws   = (float*)d_ws;
  float* part = ws;                   // 64*16*512      =   524,288
  float* seq  = part + 524288;        // 64*512         =    32,768
  float* diff = seq + 32768;          //                =    32,768
  float* pre  = diff + 32768;         // 64*1536        =    98,304
  float* act  = pre + 98304;          //                =    98,304
  float* lg   = act + 98304;          // 64*4           =       256
  float* ls   = lg + 256;             // 64*3072        =   196,608
  float* la   = ls + 196608;          // 64*2048        =   131,072
  float* klacc = la + 131072;         // 3              (total ~4.3 MB)

  float* out = (float*)d_out;

  hipLaunchKernelGGL(k_partial, dim3(1024), dim3(256), 0, stream, x, part, klacc);
  hipLaunchKernelGGL(k_means,   dim3(64),   dim3(256), 0, stream, part, x, seq, diff);
  hipLaunchKernelGGL(k_gemm1,   dim3(192),  dim3(256), 0, stream,
                     seq, diff, gW1, gb1, sW1, sb1, aW1, ab1, pre);
  hipLaunchKernelGGL(k_act,     dim3(64),   dim3(256), 0, stream, pre, g_ln_w, g_ln_b, act);
  hipLaunchKernelGGL(k_gemm2,   dim3(648),  dim3(256), 0, stream,
                     act, gW2, gb2, sW2, sb2, aW2, ab2, lg, ls, la);
  hipLaunchKernelGGL(k_final,   dim3(256),  dim3(128), 0, stream,
                     lg, ls, la, g_prior, s_prior, a_prior, g2f, semb, aemb, out, klacc);
  hipLaunchKernelGGL(k_scalars, dim3(1),    dim3(64),  0, stream, klacc, out);
}